// Round 2
// 421.734 us; speedup vs baseline: 1.0216x; 1.0216x over previous
//
#include <hip/hip_runtime.h>

// FeatureExtractor via MFMA bf16 hi/lo, TRANSPOSED orientation, barrier-free,
// SOFTWARE-PIPELINED — minimal diff from the verified R0 kernel.
// Data layout, guards, loads, stores: IDENTICAL to R0 (bias channels at
// sp ch20 / sh ch25; q==0-guarded p1 store; q==2 scalar h store; guarded
// k<CC x prefetch). Only the schedule changed: gx(t+1) = Wih*p(t+1)+bih
// (x-split, proj, LeakyReLU, p LDS exchange, 18 ih-MFMAs) is computed
// between gru_step(t) and gru_step(t+1) into register double-buffers, so the
// recurrent critical path is only: h LDS read -> split -> 3-deep hh-MFMA
// chains (seeded with precomputed gx, same accumulation order as R0 ->
// bit-identical) -> nonlinearity -> h store.
//
// Layouts per verified guide mapping: A[m][k]/B[k][n]: m|n=lane&15,
// k=(lane>>4)*8+j; D: col=lane&15, row=(lane>>4)*4+reg.

typedef __bf16 bf16x8 __attribute__((ext_vector_type(8)));
typedef float  f32x4  __attribute__((ext_vector_type(4)));

#define TT 128
#define CC 25
#define PP 20
#define HH 25
#define NSEQ 16384
#define S  36          // LDS row stride (floats)
#define MFMA __builtin_amdgcn_mfma_f32_16x16x32_bf16

__device__ __forceinline__ void split2(float f, __bf16& hi, __bf16& lo) {
    hi = (__bf16)f;
    lo = (__bf16)(f - (float)hi);
}
__device__ __forceinline__ float sigm(float v) { return 1.f / (1.f + __expf(-v)); }

__global__ __launch_bounds__(64, 1) void gru_mfma_t(
    const float* __restrict__ x,   const float* __restrict__ W1,
    const float* __restrict__ b1,  const float* __restrict__ Wih,
    const float* __restrict__ Whh, const float* __restrict__ bih,
    const float* __restrict__ bhh, float* __restrict__ out)
{
    __shared__ float sp[16 * S];        // p rows: ch0-19 p, ch20 = 1.0 (bias)
    __shared__ float sh[2][16 * S];     // h rows: ch0-24 h, ch25 = 1.0 (bias)

    const int lane = threadIdx.x;
    const int m = lane & 15, q = lane >> 4;
    const int n0 = blockIdx.x * 16;

    // ---- LDS init: zeros + bias channels (same as R0) ----
    for (int idx = lane; idx < 16 * S; idx += 64) {
        sp[idx] = 0.f; sh[0][idx] = 0.f; sh[1][idx] = 0.f;
    }
    __syncthreads();
    if (lane < 16) {
        sp[lane * S + PP]    = 1.0f;
        sh[0][lane * S + HH] = 1.0f;
        sh[1][lane * S + HH] = 1.0f;
    }
    __syncthreads();   // once, outside the loop

    // ---- weight A-fragments (same as R0; bias at k==PP/HH/CC) ----
    bf16x8 WihH[6], WihL[6], WhhH[6], WhhL[6], W1H[2], W1L[2];
    #pragma unroll
    for (int tt = 0; tt < 6; ++tt) {
        const int g = tt >> 1;                 // 0=r,1=z,2=n
        const int u = (tt & 1) * 16 + m;       // unit within gate
        const bool uv = (u < HH);
        const int row = g * HH + u;
        bf16x8 ih, il, hh, hl;
        #pragma unroll
        for (int j = 0; j < 8; ++j) {
            const int k = q * 8 + j;
            float vih = 0.f, vhh = 0.f;
            if (uv) {
                if (k < PP)       vih = Wih[row * PP + k];
                else if (k == PP) vih = bih[row];
                if (k < HH)       vhh = Whh[row * HH + k];
                else if (k == HH) vhh = bhh[row];
            }
            __bf16 a, b;
            split2(vih, a, b); ih[j] = a; il[j] = b;
            split2(vhh, a, b); hh[j] = a; hl[j] = b;
        }
        WihH[tt] = ih; WihL[tt] = il; WhhH[tt] = hh; WhhL[tt] = hl;
    }
    #pragma unroll
    for (int tt = 0; tt < 2; ++tt) {
        const int u = tt * 16 + m;
        const bool uv = (u < PP);
        bf16x8 h8, l8;
        #pragma unroll
        for (int j = 0; j < 8; ++j) {
            const int k = q * 8 + j;
            float v = 0.f;
            if (uv) {
                if (k < CC)       v = W1[u * CC + k];
                else if (k == CC) v = b1[u];
            }
            __bf16 a, b; split2(v, a, b); h8[j] = a; l8[j] = b;
        }
        W1H[tt] = h8; W1L[tt] = l8;
    }

    // ---- x fragment (same as R0): lane holds seq m, channels q*8..q*8+7 ----
    const float* xrow = x + (size_t)(n0 + m) * (TT * CC);
    float xc[8];
    #pragma unroll
    for (int j = 0; j < 8; ++j) {
        const int k = q * 8 + j;
        xc[j] = (k < CC) ? xrow[k] : (k == CC ? 1.0f : 0.f);
    }

    struct GX { f32x4 r[2], z[2], n[2]; };

    // ---- independent half: gx from current xc; prefetch x(tn) into xc ----
    auto compute_gx = [&](int tn, GX& g) {
        bf16x8 xH, xL;
        #pragma unroll
        for (int j = 0; j < 8; ++j) { __bf16 a,b; split2(xc[j],a,b); xH[j]=a; xL[j]=b; }

        // prefetch next x (guarded, same as R0; bias/0 slots retained)
        {
            const float* xr = xrow + tn * CC;
            #pragma unroll
            for (int j = 0; j < 8; ++j) {
                const int k = q * 8 + j;
                if (k < CC) xc[j] = xr[k];
            }
        }

        // proj: P[unit][seq] = W1aug * [x;1]  (3-term hi/lo)
        f32x4 p0 = {0.f,0.f,0.f,0.f}, p1 = {0.f,0.f,0.f,0.f};
        p0 = MFMA(W1H[0], xH, p0, 0,0,0);
        p0 = MFMA(W1H[0], xL, p0, 0,0,0);
        p0 = MFMA(W1L[0], xH, p0, 0,0,0);
        p1 = MFMA(W1H[1], xH, p1, 0,0,0);
        p1 = MFMA(W1H[1], xL, p1, 0,0,0);
        p1 = MFMA(W1L[1], xH, p1, 0,0,0);
        #pragma unroll
        for (int r = 0; r < 4; ++r) {
            p0[r] = (p0[r] >= 0.f) ? p0[r] : 0.01f * p0[r];
            p1[r] = (p1[r] >= 0.f) ? p1[r] : 0.01f * p1[r];
        }

        // p -> LDS (same guarded stores as R0)
        *(f32x4*)(sp + m * S + 4 * q) = p0;
        if (q == 0) *(f32x4*)(sp + m * S + 16) = p1;

        f32x4 pa = ((const f32x4*)(sp + m * S + 8 * q))[0];
        f32x4 pb = ((const f32x4*)(sp + m * S + 8 * q))[1];
        bf16x8 pH, pL;
        #pragma unroll
        for (int j = 0; j < 4; ++j) {
            __bf16 a, b;
            split2(pa[j], a, b); pH[j]   = a; pL[j]   = b;
            split2(pb[j], a, b); pH[4+j] = a; pL[4+j] = b;
        }

        // ih gate pre-activations (zero-init; same 3-term order as R0)
        #pragma unroll
        for (int tp = 0; tp < 2; ++tp) {
            f32x4 acc = {0.f,0.f,0.f,0.f};
            acc = MFMA(WihH[tp], pH, acc, 0,0,0);
            acc = MFMA(WihH[tp], pL, acc, 0,0,0);
            acc = MFMA(WihL[tp], pH, acc, 0,0,0);
            g.r[tp] = acc;
            f32x4 az = {0.f,0.f,0.f,0.f};
            az = MFMA(WihH[2+tp], pH, az, 0,0,0);
            az = MFMA(WihH[2+tp], pL, az, 0,0,0);
            az = MFMA(WihL[2+tp], pH, az, 0,0,0);
            g.z[tp] = az;
            f32x4 an = {0.f,0.f,0.f,0.f};
            an = MFMA(WihH[4+tp], pH, an, 0,0,0);
            an = MFMA(WihH[4+tp], pL, an, 0,0,0);
            an = MFMA(WihL[4+tp], pH, an, 0,0,0);
            g.n[tp] = an;
        }
    };

    float ho[2][4] = {{0.f,0.f,0.f,0.f},{0.f,0.f,0.f,0.f}};

    // ---- recurrent half: hh MFMAs on precomputed gx + nonlinearity ----
    auto gru_step = [&](int t, const GX& g) {
        const float* hrow = sh[t & 1] + m * S + 8 * q;
        f32x4 ha = ((const f32x4*)hrow)[0];
        f32x4 hb = ((const f32x4*)hrow)[1];
        bf16x8 hH, hL;
        #pragma unroll
        for (int j = 0; j < 4; ++j) {
            __bf16 a, b;
            split2(ha[j], a, b); hH[j]   = a; hL[j]   = b;
            split2(hb[j], a, b); hH[4+j] = a; hL[4+j] = b;
        }
        f32x4 aR[2], aZ[2], aHn[2];
        #pragma unroll
        for (int tp = 0; tp < 2; ++tp) {
            f32x4 acc = g.r[tp];                      // = ih terms, same order
            acc = MFMA(WhhH[tp], hH, acc, 0,0,0);
            acc = MFMA(WhhH[tp], hL, acc, 0,0,0);
            acc = MFMA(WhhL[tp], hH, acc, 0,0,0);
            aR[tp] = acc;
            f32x4 az = g.z[tp];
            az = MFMA(WhhH[2+tp], hH, az, 0,0,0);
            az = MFMA(WhhH[2+tp], hL, az, 0,0,0);
            az = MFMA(WhhL[2+tp], hH, az, 0,0,0);
            aZ[tp] = az;
            f32x4 ah = {0.f,0.f,0.f,0.f};
            ah = MFMA(WhhH[4+tp], hH, ah, 0,0,0);
            ah = MFMA(WhhH[4+tp], hL, ah, 0,0,0);
            ah = MFMA(WhhL[4+tp], hH, ah, 0,0,0);
            aHn[tp] = ah;
        }
        // nonlinearity + h update + store to next buffer (same guards as R0)
        #pragma unroll
        for (int tp = 0; tp < 2; ++tp) {
            f32x4 hv;
            #pragma unroll
            for (int r = 0; r < 4; ++r) {
                const float rg = sigm(aR[tp][r]);
                const float zg = sigm(aZ[tp][r]);
                const float nv = g.n[tp][r] + rg * aHn[tp][r];
                const float e  = __expf(-2.f * nv);
                const float ng = 2.f / (1.f + e) - 1.f;          // tanh
                const float h2 = zg * (ho[tp][r] - ng) + ng;     // (1-z)n + z h
                ho[tp][r] = h2; hv[r] = h2;
            }
            float* dst = sh[(t + 1) & 1] + m * S + tp * 16 + 4 * q;
            if (tp == 0) {
                *(f32x4*)dst = hv;
            } else {
                if (q < 2)       *(f32x4*)dst = hv;     // units 16-23
                else if (q == 2) dst[0] = hv[0];        // unit 24 (25-27 stay pad)
            }
        }
    };

    // ---- pipelined main loop (unroll x2, named A/B gx buffers) ----
    // Invariant at iter-t entry: xc = x(t+1) channels, A = gx(t).
    GX A, B;
    compute_gx(1, A);                    // gx(0); prefetch x(1)

    for (int t = 0; t < TT; t += 2) {
        const int t2 = (t + 2 < TT) ? t + 2 : TT - 1;
        const int t3 = (t + 3 < TT) ? t + 3 : TT - 1;
        compute_gx(t2, B);               // gx(t+1); prefetch x(t+2)
        gru_step(t, A);
        compute_gx(t3, A);               // gx(t+2); prefetch x(t+3)
        gru_step(t + 1, B);
    }

    // ---- epilogue: out[seq][unit] (same as R0) ----
    float* orow = out + (size_t)(n0 + m) * HH;
    #pragma unroll
    for (int tp = 0; tp < 2; ++tp) {
        #pragma unroll
        for (int r = 0; r < 4; ++r) {
            const int u = tp * 16 + 4 * q + r;
            if (u < HH) orow[u] = ho[tp][r];
        }
    }
}

extern "C" void kernel_launch(void* const* d_in, const int* in_sizes, int n_in,
                              void* d_out, int out_size, void* d_ws, size_t ws_size,
                              hipStream_t stream) {
    const float* x   = (const float*)d_in[0];
    const float* W1  = (const float*)d_in[1];
    const float* b1  = (const float*)d_in[2];
    const float* Wih = (const float*)d_in[3];
    const float* Whh = (const float*)d_in[4];
    const float* bih = (const float*)d_in[5];
    const float* bhh = (const float*)d_in[6];
    float* out = (float*)d_out;

    gru_mfma_t<<<NSEQ / 16, 64, 0, stream>>>(x, W1, b1, Wih, Whh, bih, bhh, out);
}